// Round 9
// baseline (436.192 us; speedup 1.0000x reference)
//
#include <hip/hip_runtime.h>
#include <stdint.h>

// ---------------------------------------------------------------------------
// Predictor: MLP (256->512->256->128) -> LSTM(128 in, 256 hidden, T=50)
// v8: TWO launches (pack_all + lstm_fused).
//   lstm_fused: 256 blocks x 512 thr, 16 batch rows/block.
//   PROLOGUE: in-block MLP chain (zs->split->h1->h2->zb->xpreg), B operands
//   pre-packed fragments from L2, stage outputs in LDS A-fragment layout.
//   W_hh register loads issued before the stage-D barrier (latency hides
//   under barrier + whh_lds fill).
//   MAIN LOOP (v8): ZERO L2 streaming. W_hh residency:
//     slices 0..5 -> PERSISTENT REGISTERS (192 regs/wave; net-zero vs v7:
//                    +32 pers, -32 stream buffer)
//     slices 6,7  -> LDS (128 KB, ds_read_b128 at consume)
//   Only VMEM in the t-loop = NT output stores. L2 stream ladder:
//   512 (v2) -> 384 -> 192 -> 128 -> 64 -> 0 KB/CU/step.
//   kt->slice mapping unchanged -> bitwise-identical output (absmax 2^-9).
// ---------------------------------------------------------------------------

typedef short short8 __attribute__((ext_vector_type(8)));
typedef float floatx4 __attribute__((ext_vector_type(4)));

#define BATCH 4096
#define HID 256
#define TSTEPS 50

static __device__ __forceinline__ unsigned short f2bf(float x) {
  union { float f; unsigned int u; } v; v.f = x;
  unsigned int r = (v.u + 0x7fffu + ((v.u >> 16) & 1u)) >> 16;  // RNE
  return (unsigned short)r;
}
static __device__ __forceinline__ float bf2f(unsigned short h) {
  union { unsigned int u; float f; } v; v.u = ((unsigned int)h) << 16;
  return v.f;
}
static __device__ __forceinline__ float sigmf(float x) {
  return __builtin_amdgcn_rcpf(1.0f + __expf(-x));
}
static __device__ __forceinline__ float tanhf_(float x) {
  return 1.0f - 2.0f * __builtin_amdgcn_rcpf(__expf(2.0f * x) + 1.0f);
}

// lgkm-only barrier: LDS visibility without draining the vmcnt queue.
static __device__ __forceinline__ void lds_barrier() {
  __asm__ volatile("s_waitcnt lgkmcnt(0)\n\ts_barrier" ::: "memory");
}

// ---------------------------------------------------------------------------
// pack_all: weights -> B-fragment layout.
//   Fragment (nt,kt): lane holds B[n = nt*16 + (lane&15)][kt*32 + (lane>>4)*8
//   + j], j=0..7; stored at frag[(nt*NKT + kt)*64 + lane][8].
//   blocks [0,64):    W1  [512,256]  -> w1fh/w1fl   (NKT=8)
//   blocks [64,128):  W2  [256,512]  -> w2fh/w2fl   (NKT=16)
//   blocks [128,144): W3  [128,256]  -> w3fh/w3fl   (NKT=8)
//   blocks [144,208): Wih [1024,128] -> wifh/wifl   (NKT=4)
//   blocks [208,336): W_hh[1024,256] -> whhf, wave-interleaved layout
//                     idx = ((kt*8+w)*8+i)*64+lane, nt = (i>>1)*16+w*2+(i&1)
// ---------------------------------------------------------------------------
__global__ __launch_bounds__(256) void pack_all(
    const float* __restrict__ W1, const float* __restrict__ W2,
    const float* __restrict__ W3, const float* __restrict__ Wih,
    const float* __restrict__ Whh,
    unsigned short* __restrict__ w1fh, unsigned short* __restrict__ w1fl,
    unsigned short* __restrict__ w2fh, unsigned short* __restrict__ w2fl,
    unsigned short* __restrict__ w3fh, unsigned short* __restrict__ w3fl,
    unsigned short* __restrict__ wifh, unsigned short* __restrict__ wifl,
    unsigned short* __restrict__ whhf) {
  const int bid = blockIdx.x;
  const int tid = threadIdx.x;
  if (bid < 208) {  // hi/lo split-bf16 B-fragment packs
    const float* W; unsigned short *dh, *dl; int NKT, K, idx;
    if (bid < 64)       { W = W1;  dh = w1fh; dl = w1fl; NKT = 8;  K = 256; idx = bid * 256 + tid; }
    else if (bid < 128) { W = W2;  dh = w2fh; dl = w2fl; NKT = 16; K = 512; idx = (bid - 64) * 256 + tid; }
    else if (bid < 144) { W = W3;  dh = w3fh; dl = w3fl; NKT = 8;  K = 256; idx = (bid - 128) * 256 + tid; }
    else                { W = Wih; dh = wifh; dl = wifl; NKT = 4;  K = 128; idx = (bid - 144) * 256 + tid; }
    const int lane = idx & 63, f = idx >> 6;
    const int nt = f / NKT, kt = f - nt * NKT;
    const int n = nt * 16 + (lane & 15);
    const int k0 = kt * 32 + (lane >> 4) * 8;
    const float* src = W + (size_t)n * K + k0;
#pragma unroll
    for (int j = 0; j < 8; ++j) {
      float v = src[j];
      unsigned short hb = f2bf(v);
      dh[(size_t)idx * 8 + j] = hb;
      dl[(size_t)idx * 8 + j] = f2bf(v - bf2f(hb));
    }
  } else {  // W_hh pack (bf16), wave-interleaved
    const int idx = (bid - 208) * 256 + tid;
    const int lane = idx & 63;
    const int i = (idx >> 6) & 7;
    const int w = (idx >> 9) & 7;
    const int kt = idx >> 12;
    const int nt = (i >> 1) * 16 + w * 2 + (i & 1);
    const int n = nt * 16 + (lane & 15);
    const int k0 = kt * 32 + (lane >> 4) * 8;
    const float* src = Whh + (size_t)n * 256 + k0;
    unsigned short* dst = whhf + (size_t)idx * 8;
#pragma unroll
    for (int j = 0; j < 8; ++j) dst[j] = f2bf(src[j]);
  }
}

// ---------------------------------------------------------------------------
// One MLP stage (16 rows x 16*?: per-wave n-tile), split-bf16 MFMA, output
// written to LDS in A-fragment layout (same math as the h_frag write).
// ---------------------------------------------------------------------------
template <int NKT, int RELU>
static __device__ __forceinline__ void mlp_stage(
    const unsigned short (*ah)[64][8], const unsigned short (*al)[64][8],
    const unsigned short* __restrict__ bfh, const unsigned short* __restrict__ bfl,
    int nt, const float* __restrict__ bias,
    unsigned short (*oh)[64][8], unsigned short (*ol)[64][8],
    int lane, int quad, int l16) {
  floatx4 acc = {};
  const size_t base = ((size_t)(nt * NKT) * 64 + lane) * 8;
#pragma unroll
  for (int kt = 0; kt < NKT; ++kt) {
    short8 a_h = *(const short8*)&ah[kt][lane][0];
    short8 a_l = *(const short8*)&al[kt][lane][0];
    short8 b_h = *(const short8*)(bfh + base + kt * 512);
    short8 b_l = *(const short8*)(bfl + base + kt * 512);
    acc = __builtin_amdgcn_mfma_f32_16x16x32_bf16(a_l, b_h, acc, 0, 0, 0);
    acc = __builtin_amdgcn_mfma_f32_16x16x32_bf16(a_h, b_l, acc, 0, 0, 0);
    acc = __builtin_amdgcn_mfma_f32_16x16x32_bf16(a_h, b_h, acc, 0, 0, 0);
  }
  const int col = nt * 16 + l16;
  const float bj = bias[col];
  const int kt2 = col >> 5, lhi = ((col >> 3) & 3) << 4, j2 = col & 7;
#pragma unroll
  for (int r = 0; r < 4; ++r) {
    float v = acc[r] + bj;
    if (RELU) v = fmaxf(v, 0.f);
    unsigned short hb = f2bf(v);
    oh[kt2][(quad * 4 + r) | lhi][j2] = hb;
    ol[kt2][(quad * 4 + r) | lhi][j2] = f2bf(v - bf2f(hb));
  }
}

// ---------------------------------------------------------------------------
// Fused MLP + persistent LSTM. 256 blocks x 512 threads (8 waves), 16 rows.
// ---------------------------------------------------------------------------
__global__ __launch_bounds__(512, 2) void lstm_fused(
    const float* __restrict__ zs,             // [4096,256] fp32
    const float* __restrict__ b1, const float* __restrict__ b2,
    const float* __restrict__ b3,
    const float* __restrict__ bih, const float* __restrict__ bhh,
    const unsigned short* __restrict__ w1fh, const unsigned short* __restrict__ w1fl,
    const unsigned short* __restrict__ w2fh, const unsigned short* __restrict__ w2fl,
    const unsigned short* __restrict__ w3fh, const unsigned short* __restrict__ w3fl,
    const unsigned short* __restrict__ wifh, const unsigned short* __restrict__ wifl,
    const unsigned short* __restrict__ whhf,  // packed bf16 fragments
    float* __restrict__ out) {                // [4096,50,256] fp32
  __shared__ __align__(16) unsigned char smem[147456];
  // steady state: whh_lds [0,131072), h_frag [131072,147456)
  unsigned short* whh_lds = (unsigned short*)smem;
  unsigned short (*h_frag)[8][64][8] = (unsigned short(*)[8][64][8])(smem + 131072);
  // prologue aliases (inside the whh_lds region; dead before whh_lds fill)
  unsigned short (*zsh)[64][8] = (unsigned short(*)[64][8])(smem + 0);      // 8K
  unsigned short (*zsl)[64][8] = (unsigned short(*)[64][8])(smem + 8192);   // 8K
  unsigned short (*h1h)[64][8] = (unsigned short(*)[64][8])(smem + 16384);  // 16K
  unsigned short (*h1l)[64][8] = (unsigned short(*)[64][8])(smem + 32768);  // 16K
  unsigned short (*h2h)[64][8] = (unsigned short(*)[64][8])(smem + 49152);  // 8K
  unsigned short (*h2l)[64][8] = (unsigned short(*)[64][8])(smem + 57344);  // 8K
  unsigned short (*zbh)[64][8] = (unsigned short(*)[64][8])(smem + 65536);  // 4K
  unsigned short (*zbl)[64][8] = (unsigned short(*)[64][8])(smem + 69632);  // 4K

  const int tid = threadIdx.x;
  const int wave = tid >> 6;
  const int lane = tid & 63;
  const int quad = lane >> 4;
  const int l16 = lane & 15;
  const int block_m = blockIdx.x * 16;
  const int ut0 = wave * 2;

  // h_frag zero-init (disjoint from prologue region)
  for (int i = tid; i < 2 * 8 * 64 * 8; i += 512)
    ((unsigned short*)(smem + 131072))[i] = 0;

  // ---- MLP prologue ----
  // zs tile -> split-bf16 A-fragments. thread = (kt = tid>>6, lane)
  {
    const int kt = tid >> 6;  // 0..7
    const float* zrow =
        zs + (size_t)(block_m + l16) * 256 + kt * 32 + quad * 8;
    float4 z0 = *(const float4*)zrow;
    float4 z1 = *(const float4*)(zrow + 4);
    float zz[8] = {z0.x, z0.y, z0.z, z0.w, z1.x, z1.y, z1.z, z1.w};
#pragma unroll
    for (int j = 0; j < 8; ++j) {
      unsigned short hb = f2bf(zz[j]);
      zsh[kt][lane][j] = hb;
      zsl[kt][lane][j] = f2bf(zz[j] - bf2f(hb));
    }
  }
  lds_barrier();

  // Stage A: h1[16,512] = relu(zs @ W1^T + b1); wave w owns n-tiles 4w..4w+3
#pragma unroll
  for (int ntl = 0; ntl < 4; ++ntl)
    mlp_stage<8, 1>(zsh, zsl, w1fh, w1fl, wave * 4 + ntl, b1, h1h, h1l,
                    lane, quad, l16);
  lds_barrier();

  // Stage B: h2[16,256] = relu(h1 @ W2^T + b2); n-tiles 2w, 2w+1
#pragma unroll
  for (int ntl = 0; ntl < 2; ++ntl)
    mlp_stage<16, 1>(h1h, h1l, w2fh, w2fl, wave * 2 + ntl, b2, h2h, h2l,
                     lane, quad, l16);
  lds_barrier();

  // Stage C: zb[16,128] = h2 @ W3^T + b3; n-tile w
  mlp_stage<8, 0>(h2h, h2l, w3fh, w3fl, wave, b3, zbh, zbl, lane, quad, l16);
  lds_barrier();

  // Stage D: xpreg = zb @ Wih^T + bih + bhh  (MFMA C-layout == xpreg layout)
  floatx4 xpreg[8];
#pragma unroll
  for (int i = 0; i < 8; ++i) {
    const int nt = (i >> 1) * 16 + wave * 2 + (i & 1);
    floatx4 acc = {};
    const size_t base = ((size_t)(nt * 4) * 64 + lane) * 8;
#pragma unroll
    for (int kt = 0; kt < 4; ++kt) {
      short8 a_h = *(const short8*)&zbh[kt][lane][0];
      short8 a_l = *(const short8*)&zbl[kt][lane][0];
      short8 b_h = *(const short8*)(wifh + base + kt * 512);
      short8 b_l = *(const short8*)(wifl + base + kt * 512);
      acc = __builtin_amdgcn_mfma_f32_16x16x32_bf16(a_l, b_h, acc, 0, 0, 0);
      acc = __builtin_amdgcn_mfma_f32_16x16x32_bf16(a_h, b_l, acc, 0, 0, 0);
      acc = __builtin_amdgcn_mfma_f32_16x16x32_bf16(a_h, b_h, acc, 0, 0, 0);
    }
    const int col = nt * 16 + l16;
    const float bj = bih[col] + bhh[col];
#pragma unroll
    for (int r = 0; r < 4; ++r) xpreg[i][r] = acc[r] + bj;
  }

  // PERSISTENT register slices 0..5 (t-invariant): issued HERE (before the
  // stage-D barrier + whh_lds fill) so their L2 latency hides under the
  // barrier drain and the 128 KB LDS fill. Net-zero regs vs v7 (+32 pers,
  // -32 stream buffer).
  short8 pers[6][8];
  {
#pragma unroll
    for (int sl = 0; sl < 6; ++sl) {
      const unsigned short* p =
          whhf + ((size_t)((sl * 8 + wave) * 8) * 64 + lane) * 8;
#pragma unroll
      for (int i = 0; i < 8; ++i) pers[sl][i] = *(const short8*)(p + i * 512);
    }
  }

  lds_barrier();  // zb reads complete before whh_lds overwrites the region

  // ---- LSTM setup ----
  // LDS-cache W_hh slices 6,7 (whhf shorts [196608, 262144), 128 KB)
  {
    const short8* s = (const short8*)(whhf + 196608);
    short8* d = (short8*)whh_lds;
    for (int i = tid; i < 8192; i += 512) d[i] = s[i];
  }

  float c[2][4] = {};

  __syncthreads();

  const size_t orow = (size_t)TSTEPS * HID;
  int cur = 0;

#pragma unroll 1
  for (int t = 0; t < TSTEPS; ++t) {
    // launder: keep LDS B reads un-hoisted (address not t-invariant-folded)
    unsigned lofs = 0;
    asm volatile("" : "+v"(lofs));

    floatx4 acc[8];

    // rolling A-fragment (h) prefetch, depth 1, within-step only
    short8 aab[2];
    aab[0] = *(const short8*)&h_frag[cur][0][lane][0];

#pragma unroll
    for (int kt = 0; kt < 8; ++kt) {
      const short8 a = aab[kt & 1];
      if (kt < 7)  // next A-frag from LDS (cur buffer fully written)
        aab[(kt + 1) & 1] = *(const short8*)&h_frag[cur][kt + 1][lane][0];

      if (kt == 0) {
#pragma unroll
        for (int i = 0; i < 8; ++i)
          acc[i] = __builtin_amdgcn_mfma_f32_16x16x32_bf16(a, pers[0][i],
                                                           xpreg[i], 0, 0, 0);
      } else if (kt < 6) {
#pragma unroll
        for (int i = 0; i < 8; ++i)
          acc[i] = __builtin_amdgcn_mfma_f32_16x16x32_bf16(a, pers[kt][i],
                                                           acc[i], 0, 0, 0);
      } else {  // kt = 6,7: B from LDS (slices 6,7)
#pragma unroll
        for (int i = 0; i < 8; ++i) {
          const short8 bl = *(const short8*)&whh_lds[
              lofs + (size_t)((((kt - 6) * 8 + wave) * 8 + i) * 512) + lane * 8];
          acc[i] = __builtin_amdgcn_mfma_f32_16x16x32_bf16(a, bl, acc[i],
                                                           0, 0, 0);
        }
      }
    }

    const int nxt = cur ^ 1;
#pragma unroll
    for (int utl = 0; utl < 2; ++utl) {
      floatx4 gi = acc[0 + utl];
      floatx4 gf = acc[2 + utl];
      floatx4 gg = acc[4 + utl];
      floatx4 go = acc[6 + utl];
      const int u = (ut0 + utl) * 16 + l16;
      const int kt2 = u >> 5;
      const int lhi = ((u >> 3) & 3) << 4;
      const int j2 = u & 7;
#pragma unroll
      for (int r = 0; r < 4; ++r) {
        float iv = sigmf(gi[r]);
        float fv = sigmf(gf[r]);
        float gv = tanhf_(gg[r]);
        float ov = sigmf(go[r]);
        float cv = fmaf(fv, c[utl][r], iv * gv);
        c[utl][r] = cv;
        float hv = ov * tanhf_(cv);
        int mloc = quad * 4 + r;
        // non-temporal: don't let the 205 MB out-stream evict W_hh from L2
        __builtin_nontemporal_store(
            hv, &out[(size_t)(block_m + mloc) * orow + (size_t)t * HID + u]);
        h_frag[nxt][kt2][mloc | lhi][j2] = f2bf(hv);
      }
    }
    cur = nxt;
    lds_barrier();  // h_frag visibility only; vmcnt queue keeps flowing
  }
}

// ---------------------------------------------------------------------------
extern "C" void kernel_launch(void* const* d_in, const int* in_sizes, int n_in,
                              void* d_out, int out_size, void* d_ws, size_t ws_size,
                              hipStream_t stream) {
  const float* zs  = (const float*)d_in[0];
  const float* W1  = (const float*)d_in[1];
  const float* b1  = (const float*)d_in[2];
  const float* W2  = (const float*)d_in[3];
  const float* b2  = (const float*)d_in[4];
  const float* W3  = (const float*)d_in[5];
  const float* b3  = (const float*)d_in[6];
  const float* Wih = (const float*)d_in[7];
  const float* Whh = (const float*)d_in[8];
  const float* bih = (const float*)d_in[9];
  const float* bhh = (const float*)d_in[10];
  float* out = (float*)d_out;

  char* ws = (char*)d_ws;
  const size_t KB = 1024;
  unsigned short* w1fh = (unsigned short*)(ws + 0);            // 256 KB
  unsigned short* w1fl = (unsigned short*)(ws + 256 * KB);     // 256 KB
  unsigned short* w2fh = (unsigned short*)(ws + 512 * KB);     // 256 KB
  unsigned short* w2fl = (unsigned short*)(ws + 768 * KB);     // 256 KB
  unsigned short* w3fh = (unsigned short*)(ws + 1024 * KB);    // 64 KB
  unsigned short* w3fl = (unsigned short*)(ws + 1088 * KB);    // 64 KB
  unsigned short* wifh = (unsigned short*)(ws + 1152 * KB);    // 256 KB
  unsigned short* wifl = (unsigned short*)(ws + 1408 * KB);    // 256 KB
  unsigned short* whhf = (unsigned short*)(ws + 2048 * KB);    // 512 KB

  // 1) all weights -> fragment layouts (one small launch)
  pack_all<<<336, 256, 0, stream>>>(W1, W2, W3, Wih, Whh,
                                    w1fh, w1fl, w2fh, w2fl, w3fh, w3fl,
                                    wifh, wifl, whhf);

  // 2) fused MLP prologue + persistent LSTM
  lstm_fused<<<BATCH / 16, 512, 0, stream>>>(
      zs, b1, b2, b3, bih, bhh, w1fh, w1fl, w2fh, w2fl, w3fh, w3fl,
      wifh, wifl, whhf, out);
}

// Round 10
// 347.696 us; speedup vs baseline: 1.2545x; 1.2545x over previous
//
#include <hip/hip_runtime.h>
#include <stdint.h>

// ---------------------------------------------------------------------------
// Predictor: MLP (256->512->256->128) -> LSTM(128 in, 256 hidden, T=50)
// v7 (REVERT from v8): TWO launches (pack_all + lstm_fused).
//   v8 post-mortem: promoting slice 0 to a 6th persistent register slice
//   spilled to scratch (FETCH +10.5 MB, WRITE +21 MB, dur 174->266 us).
//   v7's pers-5 + 1 streamed slice is the register-packing limit.
//   lstm_fused: 256 blocks x 512 thr, 16 batch rows/block.
//   PROLOGUE: in-block MLP chain (zs->split->h1->h2->zb->xpreg), B operands
//   pre-packed fragments from L2, stage outputs in LDS A-fragment layout.
//   pers/bA W_hh register loads are issued BEFORE the stage-D barrier so
//   their latency hides under the barrier + whh_lds fill.
//   MAIN LOOP: W_hh residency
//     slices 1,2,3,4,5 -> PERSISTENT REGISTERS (160 VGPR/wave)
//     slices 6,7       -> LDS (128 KB, ds_read_b128 at consume)
//     slice  0         -> streamed from L2, ONE rolling buffer bA,
//                         refill @kt1 <- slice0' (7-phase cross-barrier
//                         issue-to-use lead, ahead of epilogue NT stores)
//   L2 stream: 64 KB/CU/step (residency ladder's register-feasible floor).
// ---------------------------------------------------------------------------

typedef short short8 __attribute__((ext_vector_type(8)));
typedef float floatx4 __attribute__((ext_vector_type(4)));

#define BATCH 4096
#define HID 256
#define TSTEPS 50

static __device__ __forceinline__ unsigned short f2bf(float x) {
  union { float f; unsigned int u; } v; v.f = x;
  unsigned int r = (v.u + 0x7fffu + ((v.u >> 16) & 1u)) >> 16;  // RNE
  return (unsigned short)r;
}
static __device__ __forceinline__ float bf2f(unsigned short h) {
  union { unsigned int u; float f; } v; v.u = ((unsigned int)h) << 16;
  return v.f;
}
static __device__ __forceinline__ float sigmf(float x) {
  return __builtin_amdgcn_rcpf(1.0f + __expf(-x));
}
static __device__ __forceinline__ float tanhf_(float x) {
  return 1.0f - 2.0f * __builtin_amdgcn_rcpf(__expf(2.0f * x) + 1.0f);
}

// lgkm-only barrier: LDS visibility without draining the vmcnt queue.
static __device__ __forceinline__ void lds_barrier() {
  __asm__ volatile("s_waitcnt lgkmcnt(0)\n\ts_barrier" ::: "memory");
}

// ---------------------------------------------------------------------------
// pack_all: weights -> B-fragment layout.
//   Fragment (nt,kt): lane holds B[n = nt*16 + (lane&15)][kt*32 + (lane>>4)*8
//   + j], j=0..7; stored at frag[(nt*NKT + kt)*64 + lane][8].
//   blocks [0,64):    W1  [512,256]  -> w1fh/w1fl   (NKT=8)
//   blocks [64,128):  W2  [256,512]  -> w2fh/w2fl   (NKT=16)
//   blocks [128,144): W3  [128,256]  -> w3fh/w3fl   (NKT=8)
//   blocks [144,208): Wih [1024,128] -> wifh/wifl   (NKT=4)
//   blocks [208,336): W_hh[1024,256] -> whhf, wave-interleaved layout
//                     idx = ((kt*8+w)*8+i)*64+lane, nt = (i>>1)*16+w*2+(i&1)
// ---------------------------------------------------------------------------
__global__ __launch_bounds__(256) void pack_all(
    const float* __restrict__ W1, const float* __restrict__ W2,
    const float* __restrict__ W3, const float* __restrict__ Wih,
    const float* __restrict__ Whh,
    unsigned short* __restrict__ w1fh, unsigned short* __restrict__ w1fl,
    unsigned short* __restrict__ w2fh, unsigned short* __restrict__ w2fl,
    unsigned short* __restrict__ w3fh, unsigned short* __restrict__ w3fl,
    unsigned short* __restrict__ wifh, unsigned short* __restrict__ wifl,
    unsigned short* __restrict__ whhf) {
  const int bid = blockIdx.x;
  const int tid = threadIdx.x;
  if (bid < 208) {  // hi/lo split-bf16 B-fragment packs
    const float* W; unsigned short *dh, *dl; int NKT, K, idx;
    if (bid < 64)       { W = W1;  dh = w1fh; dl = w1fl; NKT = 8;  K = 256; idx = bid * 256 + tid; }
    else if (bid < 128) { W = W2;  dh = w2fh; dl = w2fl; NKT = 16; K = 512; idx = (bid - 64) * 256 + tid; }
    else if (bid < 144) { W = W3;  dh = w3fh; dl = w3fl; NKT = 8;  K = 256; idx = (bid - 128) * 256 + tid; }
    else                { W = Wih; dh = wifh; dl = wifl; NKT = 4;  K = 128; idx = (bid - 144) * 256 + tid; }
    const int lane = idx & 63, f = idx >> 6;
    const int nt = f / NKT, kt = f - nt * NKT;
    const int n = nt * 16 + (lane & 15);
    const int k0 = kt * 32 + (lane >> 4) * 8;
    const float* src = W + (size_t)n * K + k0;
#pragma unroll
    for (int j = 0; j < 8; ++j) {
      float v = src[j];
      unsigned short hb = f2bf(v);
      dh[(size_t)idx * 8 + j] = hb;
      dl[(size_t)idx * 8 + j] = f2bf(v - bf2f(hb));
    }
  } else {  // W_hh pack (bf16), wave-interleaved
    const int idx = (bid - 208) * 256 + tid;
    const int lane = idx & 63;
    const int i = (idx >> 6) & 7;
    const int w = (idx >> 9) & 7;
    const int kt = idx >> 12;
    const int nt = (i >> 1) * 16 + w * 2 + (i & 1);
    const int n = nt * 16 + (lane & 15);
    const int k0 = kt * 32 + (lane >> 4) * 8;
    const float* src = Whh + (size_t)n * 256 + k0;
    unsigned short* dst = whhf + (size_t)idx * 8;
#pragma unroll
    for (int j = 0; j < 8; ++j) dst[j] = f2bf(src[j]);
  }
}

// ---------------------------------------------------------------------------
// One MLP stage (16 rows x 16*?: per-wave n-tile), split-bf16 MFMA, output
// written to LDS in A-fragment layout (same math as the h_frag write).
// ---------------------------------------------------------------------------
template <int NKT, int RELU>
static __device__ __forceinline__ void mlp_stage(
    const unsigned short (*ah)[64][8], const unsigned short (*al)[64][8],
    const unsigned short* __restrict__ bfh, const unsigned short* __restrict__ bfl,
    int nt, const float* __restrict__ bias,
    unsigned short (*oh)[64][8], unsigned short (*ol)[64][8],
    int lane, int quad, int l16) {
  floatx4 acc = {};
  const size_t base = ((size_t)(nt * NKT) * 64 + lane) * 8;
#pragma unroll
  for (int kt = 0; kt < NKT; ++kt) {
    short8 a_h = *(const short8*)&ah[kt][lane][0];
    short8 a_l = *(const short8*)&al[kt][lane][0];
    short8 b_h = *(const short8*)(bfh + base + kt * 512);
    short8 b_l = *(const short8*)(bfl + base + kt * 512);
    acc = __builtin_amdgcn_mfma_f32_16x16x32_bf16(a_l, b_h, acc, 0, 0, 0);
    acc = __builtin_amdgcn_mfma_f32_16x16x32_bf16(a_h, b_l, acc, 0, 0, 0);
    acc = __builtin_amdgcn_mfma_f32_16x16x32_bf16(a_h, b_h, acc, 0, 0, 0);
  }
  const int col = nt * 16 + l16;
  const float bj = bias[col];
  const int kt2 = col >> 5, lhi = ((col >> 3) & 3) << 4, j2 = col & 7;
#pragma unroll
  for (int r = 0; r < 4; ++r) {
    float v = acc[r] + bj;
    if (RELU) v = fmaxf(v, 0.f);
    unsigned short hb = f2bf(v);
    oh[kt2][(quad * 4 + r) | lhi][j2] = hb;
    ol[kt2][(quad * 4 + r) | lhi][j2] = f2bf(v - bf2f(hb));
  }
}

// ---------------------------------------------------------------------------
// Fused MLP + persistent LSTM. 256 blocks x 512 threads (8 waves), 16 rows.
// ---------------------------------------------------------------------------
__global__ __launch_bounds__(512, 2) void lstm_fused(
    const float* __restrict__ zs,             // [4096,256] fp32
    const float* __restrict__ b1, const float* __restrict__ b2,
    const float* __restrict__ b3,
    const float* __restrict__ bih, const float* __restrict__ bhh,
    const unsigned short* __restrict__ w1fh, const unsigned short* __restrict__ w1fl,
    const unsigned short* __restrict__ w2fh, const unsigned short* __restrict__ w2fl,
    const unsigned short* __restrict__ w3fh, const unsigned short* __restrict__ w3fl,
    const unsigned short* __restrict__ wifh, const unsigned short* __restrict__ wifl,
    const unsigned short* __restrict__ whhf,  // packed bf16 fragments
    float* __restrict__ out) {                // [4096,50,256] fp32
  __shared__ __align__(16) unsigned char smem[147456];
  // steady state: whh_lds [0,131072), h_frag [131072,147456)
  unsigned short* whh_lds = (unsigned short*)smem;
  unsigned short (*h_frag)[8][64][8] = (unsigned short(*)[8][64][8])(smem + 131072);
  // prologue aliases (inside the whh_lds region; dead before whh_lds fill)
  unsigned short (*zsh)[64][8] = (unsigned short(*)[64][8])(smem + 0);      // 8K
  unsigned short (*zsl)[64][8] = (unsigned short(*)[64][8])(smem + 8192);   // 8K
  unsigned short (*h1h)[64][8] = (unsigned short(*)[64][8])(smem + 16384);  // 16K
  unsigned short (*h1l)[64][8] = (unsigned short(*)[64][8])(smem + 32768);  // 16K
  unsigned short (*h2h)[64][8] = (unsigned short(*)[64][8])(smem + 49152);  // 8K
  unsigned short (*h2l)[64][8] = (unsigned short(*)[64][8])(smem + 57344);  // 8K
  unsigned short (*zbh)[64][8] = (unsigned short(*)[64][8])(smem + 65536);  // 4K
  unsigned short (*zbl)[64][8] = (unsigned short(*)[64][8])(smem + 69632);  // 4K

  const int tid = threadIdx.x;
  const int wave = tid >> 6;
  const int lane = tid & 63;
  const int quad = lane >> 4;
  const int l16 = lane & 15;
  const int block_m = blockIdx.x * 16;
  const int ut0 = wave * 2;

  // h_frag zero-init (disjoint from prologue region)
  for (int i = tid; i < 2 * 8 * 64 * 8; i += 512)
    ((unsigned short*)(smem + 131072))[i] = 0;

  // ---- MLP prologue ----
  // zs tile -> split-bf16 A-fragments. thread = (kt = tid>>6, lane)
  {
    const int kt = tid >> 6;  // 0..7
    const float* zrow =
        zs + (size_t)(block_m + l16) * 256 + kt * 32 + quad * 8;
    float4 z0 = *(const float4*)zrow;
    float4 z1 = *(const float4*)(zrow + 4);
    float zz[8] = {z0.x, z0.y, z0.z, z0.w, z1.x, z1.y, z1.z, z1.w};
#pragma unroll
    for (int j = 0; j < 8; ++j) {
      unsigned short hb = f2bf(zz[j]);
      zsh[kt][lane][j] = hb;
      zsl[kt][lane][j] = f2bf(zz[j] - bf2f(hb));
    }
  }
  lds_barrier();

  // Stage A: h1[16,512] = relu(zs @ W1^T + b1); wave w owns n-tiles 4w..4w+3
#pragma unroll
  for (int ntl = 0; ntl < 4; ++ntl)
    mlp_stage<8, 1>(zsh, zsl, w1fh, w1fl, wave * 4 + ntl, b1, h1h, h1l,
                    lane, quad, l16);
  lds_barrier();

  // Stage B: h2[16,256] = relu(h1 @ W2^T + b2); n-tiles 2w, 2w+1
#pragma unroll
  for (int ntl = 0; ntl < 2; ++ntl)
    mlp_stage<16, 1>(h1h, h1l, w2fh, w2fl, wave * 2 + ntl, b2, h2h, h2l,
                     lane, quad, l16);
  lds_barrier();

  // Stage C: zb[16,128] = h2 @ W3^T + b3; n-tile w
  mlp_stage<8, 0>(h2h, h2l, w3fh, w3fl, wave, b3, zbh, zbl, lane, quad, l16);
  lds_barrier();

  // Stage D: xpreg = zb @ Wih^T + bih + bhh  (MFMA C-layout == xpreg layout)
  floatx4 xpreg[8];
#pragma unroll
  for (int i = 0; i < 8; ++i) {
    const int nt = (i >> 1) * 16 + wave * 2 + (i & 1);
    floatx4 acc = {};
    const size_t base = ((size_t)(nt * 4) * 64 + lane) * 8;
#pragma unroll
    for (int kt = 0; kt < 4; ++kt) {
      short8 a_h = *(const short8*)&zbh[kt][lane][0];
      short8 a_l = *(const short8*)&zbl[kt][lane][0];
      short8 b_h = *(const short8*)(wifh + base + kt * 512);
      short8 b_l = *(const short8*)(wifl + base + kt * 512);
      acc = __builtin_amdgcn_mfma_f32_16x16x32_bf16(a_l, b_h, acc, 0, 0, 0);
      acc = __builtin_amdgcn_mfma_f32_16x16x32_bf16(a_h, b_l, acc, 0, 0, 0);
      acc = __builtin_amdgcn_mfma_f32_16x16x32_bf16(a_h, b_h, acc, 0, 0, 0);
    }
    const int col = nt * 16 + l16;
    const float bj = bih[col] + bhh[col];
#pragma unroll
    for (int r = 0; r < 4; ++r) xpreg[i][r] = acc[r] + bj;
  }

  // PERSISTENT register slices 1,2,3,4,5 + stream buffer (slice 0):
  // issued HERE (before the stage-D barrier + whh_lds fill) so their L2
  // latency hides under the barrier drain and the 128 KB LDS fill.
  short8 pers[5][8];
  short8 bA[8];
  {
#pragma unroll
    for (int sl = 0; sl < 5; ++sl) {
      const unsigned short* p =
          whhf + ((size_t)(((sl + 1) * 8 + wave) * 8) * 64 + lane) * 8;
#pragma unroll
      for (int i = 0; i < 8; ++i) pers[sl][i] = *(const short8*)(p + i * 512);
    }
    const unsigned short* w0 =
        whhf + ((size_t)((0 * 8 + wave) * 8) * 64 + lane) * 8;
#pragma unroll
    for (int i = 0; i < 8; ++i) bA[i] = *(const short8*)(w0 + i * 512);
  }

  lds_barrier();  // zb reads complete before whh_lds overwrites the region

  // ---- LSTM setup ----
  // LDS-cache W_hh slices 6,7 (whhf shorts [196608, 262144), 128 KB)
  {
    const short8* s = (const short8*)(whhf + 196608);
    short8* d = (short8*)whh_lds;
    for (int i = tid; i < 8192; i += 512) d[i] = s[i];
  }

  float c[2][4] = {};

  __syncthreads();

  const size_t orow = (size_t)TSTEPS * HID;
  int cur = 0;

#pragma unroll 1
  for (int t = 0; t < TSTEPS; ++t) {
    // launder: keep streamed B loads + LDS B reads inside the loop
    const unsigned short* wb = whhf;
    asm volatile("" : "+s"(wb));
    unsigned lofs = 0;
    asm volatile("" : "+v"(lofs));

    floatx4 acc[8];

    // rolling A-fragment (h) prefetch, depth 1, within-step only
    short8 aab[2];
    aab[0] = *(const short8*)&h_frag[cur][0][lane][0];

#pragma unroll
    for (int kt = 0; kt < 8; ++kt) {
      const short8 a = aab[kt & 1];
      if (kt < 7)  // next A-frag from LDS (cur buffer fully written)
        aab[(kt + 1) & 1] = *(const short8*)&h_frag[cur][kt + 1][lane][0];

      if (kt == 0) {
#pragma unroll
        for (int i = 0; i < 8; ++i)
          acc[i] = __builtin_amdgcn_mfma_f32_16x16x32_bf16(a, bA[i],
                                                           xpreg[i], 0, 0, 0);
      } else if (kt == 1) {
#pragma unroll
        for (int i = 0; i < 8; ++i)
          acc[i] = __builtin_amdgcn_mfma_f32_16x16x32_bf16(a, pers[0][i],
                                                           acc[i], 0, 0, 0);
        // refill bA <- next step's slice 0 (t-invariant address). 7-phase
        // issue-to-use lead (kt1 of t -> kt0 of t+1), issued ahead of the
        // epilogue's NT stores in the vmcnt FIFO. WAR on bA resolved by
        // kt0's MFMA operand reads above.
        const unsigned short* wbp =
            wb + ((size_t)((0 * 8 + wave) * 8) * 64 + lane) * 8;
#pragma unroll
        for (int i = 0; i < 8; ++i) bA[i] = *(const short8*)(wbp + i * 512);
      } else if (kt == 2) {
#pragma unroll
        for (int i = 0; i < 8; ++i)
          acc[i] = __builtin_amdgcn_mfma_f32_16x16x32_bf16(a, pers[1][i],
                                                           acc[i], 0, 0, 0);
      } else if (kt == 3) {
#pragma unroll
        for (int i = 0; i < 8; ++i)
          acc[i] = __builtin_amdgcn_mfma_f32_16x16x32_bf16(a, pers[2][i],
                                                           acc[i], 0, 0, 0);
      } else if (kt == 4) {
#pragma unroll
        for (int i = 0; i < 8; ++i)
          acc[i] = __builtin_amdgcn_mfma_f32_16x16x32_bf16(a, pers[3][i],
                                                           acc[i], 0, 0, 0);
      } else if (kt == 5) {
#pragma unroll
        for (int i = 0; i < 8; ++i)
          acc[i] = __builtin_amdgcn_mfma_f32_16x16x32_bf16(a, pers[4][i],
                                                           acc[i], 0, 0, 0);
      } else {  // kt = 6,7: B from LDS (slices 6,7)
#pragma unroll
        for (int i = 0; i < 8; ++i) {
          const short8 bl = *(const short8*)&whh_lds[
              lofs + (size_t)((((kt - 6) * 8 + wave) * 8 + i) * 512) + lane * 8];
          acc[i] = __builtin_amdgcn_mfma_f32_16x16x32_bf16(a, bl, acc[i],
                                                           0, 0, 0);
        }
      }
    }

    const int nxt = cur ^ 1;
#pragma unroll
    for (int utl = 0; utl < 2; ++utl) {
      floatx4 gi = acc[0 + utl];
      floatx4 gf = acc[2 + utl];
      floatx4 gg = acc[4 + utl];
      floatx4 go = acc[6 + utl];
      const int u = (ut0 + utl) * 16 + l16;
      const int kt2 = u >> 5;
      const int lhi = ((u >> 3) & 3) << 4;
      const int j2 = u & 7;
#pragma unroll
      for (int r = 0; r < 4; ++r) {
        float iv = sigmf(gi[r]);
        float fv = sigmf(gf[r]);
        float gv = tanhf_(gg[r]);
        float ov = sigmf(go[r]);
        float cv = fmaf(fv, c[utl][r], iv * gv);
        c[utl][r] = cv;
        float hv = ov * tanhf_(cv);
        int mloc = quad * 4 + r;
        // non-temporal: don't let the 205 MB out-stream evict W_hh from L2
        __builtin_nontemporal_store(
            hv, &out[(size_t)(block_m + mloc) * orow + (size_t)t * HID + u]);
        h_frag[nxt][kt2][mloc | lhi][j2] = f2bf(hv);
      }
    }
    cur = nxt;
    lds_barrier();  // h_frag visibility only; vmcnt queue keeps flowing
  }
}

// ---------------------------------------------------------------------------
extern "C" void kernel_launch(void* const* d_in, const int* in_sizes, int n_in,
                              void* d_out, int out_size, void* d_ws, size_t ws_size,
                              hipStream_t stream) {
  const float* zs  = (const float*)d_in[0];
  const float* W1  = (const float*)d_in[1];
  const float* b1  = (const float*)d_in[2];
  const float* W2  = (const float*)d_in[3];
  const float* b2  = (const float*)d_in[4];
  const float* W3  = (const float*)d_in[5];
  const float* b3  = (const float*)d_in[6];
  const float* Wih = (const float*)d_in[7];
  const float* Whh = (const float*)d_in[8];
  const float* bih = (const float*)d_in[9];
  const float* bhh = (const float*)d_in[10];
  float* out = (float*)d_out;

  char* ws = (char*)d_ws;
  const size_t KB = 1024;
  unsigned short* w1fh = (unsigned short*)(ws + 0);            // 256 KB
  unsigned short* w1fl = (unsigned short*)(ws + 256 * KB);     // 256 KB
  unsigned short* w2fh = (unsigned short*)(ws + 512 * KB);     // 256 KB
  unsigned short* w2fl = (unsigned short*)(ws + 768 * KB);     // 256 KB
  unsigned short* w3fh = (unsigned short*)(ws + 1024 * KB);    // 64 KB
  unsigned short* w3fl = (unsigned short*)(ws + 1088 * KB);    // 64 KB
  unsigned short* wifh = (unsigned short*)(ws + 1152 * KB);    // 256 KB
  unsigned short* wifl = (unsigned short*)(ws + 1408 * KB);    // 256 KB
  unsigned short* whhf = (unsigned short*)(ws + 2048 * KB);    // 512 KB

  // 1) all weights -> fragment layouts (one small launch)
  pack_all<<<336, 256, 0, stream>>>(W1, W2, W3, Wih, Whh,
                                    w1fh, w1fl, w2fh, w2fl, w3fh, w3fl,
                                    wifh, wifl, whhf);

  // 2) fused MLP prologue + persistent LSTM
  lstm_fused<<<BATCH / 16, 512, 0, stream>>>(
      zs, b1, b2, b3, bih, bhh, w1fh, w1fl, w2fh, w2fl, w3fh, w3fl,
      wifh, wifl, whhf, out);
}